// Round 1
// baseline (544.772 us; speedup 1.0000x reference)
//
#include <hip/hip_runtime.h>
#include <stdint.h>

#define BATCH 524288
#define OBSD  64

typedef short v8s __attribute__((ext_vector_type(8)));
typedef float v4f __attribute__((ext_vector_type(4)));

union U8 { int4 i4; v8s v; uint32_t u[4]; };

__device__ __forceinline__ uint32_t bf16rne(float f) {
  uint32_t u = __float_as_uint(f);
  return (u + 0x7fffu + ((u >> 16) & 1u)) >> 16;
}
__device__ __forceinline__ uint32_t pk2(float a, float b) {
  return bf16rne(a) | (bf16rne(b) << 16);
}

// ---- prep: fp32 weights -> bf16 (W3p negated), zero welford accumulators ----
__global__ void rnd_prep(const float* __restrict__ tW1, const float* __restrict__ tW2,
                         const float* __restrict__ tW3, const float* __restrict__ pW1,
                         const float* __restrict__ pW2, const float* __restrict__ pW3,
                         uint16_t* __restrict__ Wall, float* __restrict__ sums) {
  int i = blockIdx.x * 256 + threadIdx.x;  // grid covers exactly 81920
  if (i < 2) sums[i] = 0.0f;
  float v;
  if      (i < 8192)  v = tW1[i];
  else if (i < 24576) v = tW2[i - 8192];
  else if (i < 40960) v = tW3[i - 24576];
  else if (i < 49152) v = pW1[i - 40960];
  else if (i < 65536) v = pW2[i - 49152];
  else                v = -pW3[i - 65536];
  Wall[i] = (uint16_t)bf16rne(v);
}

// ---- main: fused dual-MLP + per-sample MSE + block welford partials ----
__global__ __launch_bounds__(256, 2) void rnd_main(
    const float* __restrict__ obs, const uint16_t* __restrict__ Wall,
    const float* __restrict__ b1t, const float* __restrict__ b2t,
    const float* __restrict__ b1p, const float* __restrict__ b2p,
    const float* __restrict__ b3t, const float* __restrict__ b3p,
    float* __restrict__ rewards, float* __restrict__ sums) {
  const int lane = threadIdx.x & 63;
  const int wv   = threadIdx.x >> 6;
  const int n    = lane & 15;
  const int q    = lane >> 4;
  const int s0   = (blockIdx.x * 4 + wv) * 32;

  const uint16_t* W1t = Wall;
  const uint16_t* W2t = W1t + 128 * 64;
  const uint16_t* W3t = W2t + 128 * 128;
  const uint16_t* W1p = W3t + 128 * 128;
  const uint16_t* W2p = W1p + 128 * 64;
  const uint16_t* W3n = W2p + 128 * 128;  // pre-negated

  uint32_t Pa[8][2][2];  // packed bf16 activations (current)
  uint32_t Pt[8][2][2];  // packed H2 of target net

  auto afrag = [&](const uint16_t* W, int K, int rt, int ks) -> v8s {
    U8 t; t.i4 = *(const int4*)(W + (rt * 16 + n) * K + ks * 32 + q * 8);
    return t.v;
  };
  auto obsfrag = [&](int ct, int ks) -> v8s {
    const float* p = obs + (size_t)(s0 + ct * 16 + n) * OBSD + ks * 32 + q * 8;
    float4 f0 = *(const float4*)p;
    float4 f1 = *(const float4*)(p + 4);
    U8 t;
    t.u[0] = pk2(f0.x, f0.y); t.u[1] = pk2(f0.z, f0.w);
    t.u[2] = pk2(f1.x, f1.y); t.u[3] = pk2(f1.z, f1.w);
    return t.v;
  };
  auto bias_init = [&](const float* b, v4f (&acc)[8][2]) {
    #pragma unroll
    for (int rt = 0; rt < 8; ++rt) {
      float4 bv = *(const float4*)(b + rt * 16 + q * 4);
      v4f c; c[0] = bv.x; c[1] = bv.y; c[2] = bv.z; c[3] = bv.w;
      acc[rt][0] = c; acc[rt][1] = c;
    }
  };
  auto pack_out = [&](v4f (&acc)[8][2], uint32_t (&P)[8][2][2], bool dorelu) {
    #pragma unroll
    for (int rt = 0; rt < 8; ++rt)
      #pragma unroll
      for (int ct = 0; ct < 2; ++ct) {
        v4f a = acc[rt][ct];
        if (dorelu) {
          a[0] = fmaxf(a[0], 0.f); a[1] = fmaxf(a[1], 0.f);
          a[2] = fmaxf(a[2], 0.f); a[3] = fmaxf(a[3], 0.f);
        }
        P[rt][ct][0] = pk2(a[0], a[1]);
        P[rt][ct][1] = pk2(a[2], a[3]);
      }
  };
  // C-layout (rows 4*qc+reg at quad qc, col n) -> B-operand layout (k=8*qb+j at quad qb)
  // via gfx950 cross-lane swaps: 2 swaps per dword pair.
  auto bfrag_from = [&](uint32_t (&P)[8][2][2], int ks, int ct) -> v8s {
    uint32_t x0 = P[2 * ks][ct][0],     x1 = P[2 * ks][ct][1];
    uint32_t y0 = P[2 * ks + 1][ct][0], y1 = P[2 * ks + 1][ct][1];
    asm("v_permlane32_swap_b32 %0, %1" : "+v"(x0), "+v"(y0));
    asm("v_permlane16_swap_b32 %0, %1" : "+v"(x0), "+v"(y0));
    asm("v_permlane32_swap_b32 %0, %1" : "+v"(x1), "+v"(y1));
    asm("v_permlane16_swap_b32 %0, %1" : "+v"(x1), "+v"(y1));
    U8 t; t.u[0] = x0; t.u[1] = x1; t.u[2] = y0; t.u[3] = y1;
    return t.v;
  };
  auto layer1 = [&](const uint16_t* W, const float* b, uint32_t (&P)[8][2][2]) {
    v4f acc[8][2];
    bias_init(b, acc);
    #pragma unroll
    for (int ks = 0; ks < 2; ++ks) {
      v8s bf0 = obsfrag(0, ks), bf1 = obsfrag(1, ks);
      #pragma unroll
      for (int rt = 0; rt < 8; ++rt) {
        v8s af = afrag(W, 64, rt, ks);
        acc[rt][0] = __builtin_amdgcn_mfma_f32_16x16x32_bf16(af, bf0, acc[rt][0], 0, 0, 0);
        acc[rt][1] = __builtin_amdgcn_mfma_f32_16x16x32_bf16(af, bf1, acc[rt][1], 0, 0, 0);
      }
    }
    pack_out(acc, P, true);
  };
  auto layer2 = [&](const uint16_t* W, const float* b, uint32_t (&Pin)[8][2][2],
                    uint32_t (&Pout)[8][2][2]) {
    v4f acc[8][2];
    bias_init(b, acc);
    #pragma unroll
    for (int ks = 0; ks < 4; ++ks) {
      v8s bf0 = bfrag_from(Pin, ks, 0), bf1 = bfrag_from(Pin, ks, 1);
      #pragma unroll
      for (int rt = 0; rt < 8; ++rt) {
        v8s af = afrag(W, 128, rt, ks);
        acc[rt][0] = __builtin_amdgcn_mfma_f32_16x16x32_bf16(af, bf0, acc[rt][0], 0, 0, 0);
        acc[rt][1] = __builtin_amdgcn_mfma_f32_16x16x32_bf16(af, bf1, acc[rt][1], 0, 0, 0);
      }
    }
    pack_out(acc, Pout, true);  // safe when Pout==Pin: all reads precede writes
  };

  // target net
  layer1(W1t, b1t, Pa);
  layer2(W2t, b2t, Pa, Pt);
  // predictor net
  layer1(W1p, b1p, Pa);
  layer2(W2p, b2p, Pa, Pa);
  // final layer: acc = (b3t-b3p) + W3t*H2t + (-W3p)*H2p  == y_t - y_p
  v4f acc[8][2];
  #pragma unroll
  for (int rt = 0; rt < 8; ++rt) {
    float4 bt = *(const float4*)(b3t + rt * 16 + q * 4);
    float4 bp = *(const float4*)(b3p + rt * 16 + q * 4);
    v4f c; c[0] = bt.x - bp.x; c[1] = bt.y - bp.y; c[2] = bt.z - bp.z; c[3] = bt.w - bp.w;
    acc[rt][0] = c; acc[rt][1] = c;
  }
  #pragma unroll
  for (int ks = 0; ks < 4; ++ks) {
    v8s bf0 = bfrag_from(Pt, ks, 0), bf1 = bfrag_from(Pt, ks, 1);
    #pragma unroll
    for (int rt = 0; rt < 8; ++rt) {
      v8s af = afrag(W3t, 128, rt, ks);
      acc[rt][0] = __builtin_amdgcn_mfma_f32_16x16x32_bf16(af, bf0, acc[rt][0], 0, 0, 0);
      acc[rt][1] = __builtin_amdgcn_mfma_f32_16x16x32_bf16(af, bf1, acc[rt][1], 0, 0, 0);
    }
  }
  #pragma unroll
  for (int ks = 0; ks < 4; ++ks) {
    v8s bf0 = bfrag_from(Pa, ks, 0), bf1 = bfrag_from(Pa, ks, 1);
    #pragma unroll
    for (int rt = 0; rt < 8; ++rt) {
      v8s af = afrag(W3n, 128, rt, ks);
      acc[rt][0] = __builtin_amdgcn_mfma_f32_16x16x32_bf16(af, bf0, acc[rt][0], 0, 0, 0);
      acc[rt][1] = __builtin_amdgcn_mfma_f32_16x16x32_bf16(af, bf1, acc[rt][1], 0, 0, 0);
    }
  }

  // epilogue: reward = mean over 128 out-dims (C rows) of diff^2
  float p0 = 0.f, p1 = 0.f;
  #pragma unroll
  for (int rt = 0; rt < 8; ++rt) {
    v4f a0 = acc[rt][0], a1 = acc[rt][1];
    p0 += a0[0]*a0[0] + a0[1]*a0[1] + a0[2]*a0[2] + a0[3]*a0[3];
    p1 += a1[0]*a1[0] + a1[1]*a1[1] + a1[2]*a1[2] + a1[3]*a1[3];
  }
  p0 += __shfl_xor(p0, 32); p0 += __shfl_xor(p0, 16);
  p1 += __shfl_xor(p1, 32); p1 += __shfl_xor(p1, 16);
  float r0 = p0 * (1.0f / 128.0f), r1 = p1 * (1.0f / 128.0f);
  if (q == 0) {
    rewards[s0 + n]      = r0;
    rewards[s0 + 16 + n] = r1;
  }
  float s = r0 + r1, ss = r0 * r0 + r1 * r1;
  s  += __shfl_xor(s, 8);  s  += __shfl_xor(s, 4);  s  += __shfl_xor(s, 2);  s  += __shfl_xor(s, 1);
  ss += __shfl_xor(ss, 8); ss += __shfl_xor(ss, 4); ss += __shfl_xor(ss, 2); ss += __shfl_xor(ss, 1);
  __shared__ float bs[4], bss[4];
  if (lane == 0) { bs[wv] = s; bss[wv] = ss; }
  __syncthreads();
  if (threadIdx.x == 0) {
    atomicAdd(&sums[0], bs[0] + bs[1] + bs[2] + bs[3]);
    atomicAdd(&sums[1], bss[0] + bss[1] + bss[2] + bss[3]);
  }
}

// ---- normalize: Chan-merge with running stats (inputs are the (1,) arrays) ----
__global__ void rnd_norm(const float* __restrict__ rewards, const float* __restrict__ sums,
                         const float* __restrict__ rm, const float* __restrict__ rm2,
                         const float* __restrict__ rc, float* __restrict__ out) {
  float S = sums[0], SS = sums[1];
  float nb = (float)BATCH;
  float bm = S / nb;
  float bm2 = SS - nb * bm * bm;          // sum((r-bm)^2)
  float cnt = rc[0];
  float newc = cnt + nb;
  float delta = bm - rm[0];
  float newmean = rm[0] + delta * nb / newc;
  float newm2 = rm2[0] + bm2 + delta * delta * cnt * nb / newc;
  float sd = (newc > 1.f) ? sqrtf(newm2 / (newc - 1.f)) : 1.f;
  float inv = 1.f / (sd + 1e-8f);
  int i = (blockIdx.x * 256 + threadIdx.x) * 4;
  float4 r = *(const float4*)(rewards + i);
  float4 o;
  o.x = (r.x - newmean) * inv; o.y = (r.y - newmean) * inv;
  o.z = (r.z - newmean) * inv; o.w = (r.w - newmean) * inv;
  *(float4*)(out + i) = o;
}

extern "C" void kernel_launch(void* const* d_in, const int* in_sizes, int n_in,
                              void* d_out, int out_size, void* d_ws, size_t ws_size,
                              hipStream_t stream) {
  const float* obs = (const float*)d_in[0];
  const float* rm  = (const float*)d_in[1];
  const float* rm2 = (const float*)d_in[2];
  const float* rc  = (const float*)d_in[3];
  const float* tW1 = (const float*)d_in[4];
  const float* tb1 = (const float*)d_in[5];
  const float* tW2 = (const float*)d_in[6];
  const float* tb2 = (const float*)d_in[7];
  const float* tW3 = (const float*)d_in[8];
  const float* tb3 = (const float*)d_in[9];
  const float* pW1 = (const float*)d_in[10];
  const float* pb1 = (const float*)d_in[11];
  const float* pW2 = (const float*)d_in[12];
  const float* pb2 = (const float*)d_in[13];
  const float* pW3 = (const float*)d_in[14];
  const float* pb3 = (const float*)d_in[15];

  float*    sums    = (float*)d_ws;                                  // 2 floats
  float*    rewards = (float*)((char*)d_ws + 256);                   // BATCH floats
  uint16_t* Wall    = (uint16_t*)((char*)d_ws + 256 + (size_t)BATCH * 4);  // 81920 bf16

  rnd_prep<<<320, 256, 0, stream>>>(tW1, tW2, tW3, pW1, pW2, pW3, Wall, sums);
  rnd_main<<<BATCH / 128, 256, 0, stream>>>(obs, Wall, tb1, tb2, pb1, pb2, tb3, pb3,
                                            rewards, sums);
  rnd_norm<<<BATCH / 1024, 256, 0, stream>>>(rewards, sums, rm, rm2, rc, (float*)d_out);
}

// Round 3
// 359.625 us; speedup vs baseline: 1.5148x; 1.5148x over previous
//
#include <hip/hip_runtime.h>
#include <stdint.h>

#define BATCH 524288
#define OBSD  64

typedef short v8s __attribute__((ext_vector_type(8)));
typedef float v4f __attribute__((ext_vector_type(4)));

union U8 { int4 i4; v8s v; uint32_t u[4]; };

__device__ __forceinline__ uint32_t bf16rne(float f) {
  uint32_t u = __float_as_uint(f);
  return (u + 0x7fffu + ((u >> 16) & 1u)) >> 16;
}
__device__ __forceinline__ uint32_t pk2(float a, float b) {
  return bf16rne(a) | (bf16rne(b) << 16);
}

// ---- prep: fp32 weights -> bf16 (W3p negated), zero welford accumulators ----
// Wall layout (elements): tW1@0(8192) tW2@8192(16384) tW3@24576(16384)
//                         pW1@40960(8192) pW2@49152(16384) -pW3@65536(16384)
__global__ void rnd_prep(const float* __restrict__ tW1, const float* __restrict__ tW2,
                         const float* __restrict__ tW3, const float* __restrict__ pW1,
                         const float* __restrict__ pW2, const float* __restrict__ pW3,
                         uint16_t* __restrict__ Wall, float* __restrict__ sums) {
  int i = blockIdx.x * 256 + threadIdx.x;  // grid covers exactly 81920
  if (i < 2) sums[i] = 0.0f;
  float v;
  if      (i < 8192)  v = tW1[i];
  else if (i < 24576) v = tW2[i - 8192];
  else if (i < 40960) v = tW3[i - 24576];
  else if (i < 49152) v = pW1[i - 40960];
  else if (i < 65536) v = pW2[i - 49152];
  else                v = -pW3[i - 65536];
  Wall[i] = (uint16_t)bf16rne(v);
}

// ---- main: R1 structure verbatim; weights staged via ONE padded LDS buffer ----
// LDS layout: plain row-major, row stride Kp = K+8 elements (+16B pad) ->
// bank-balanced for both staging writes and ds_read_b128 fragment reads.
__global__ __launch_bounds__(256, 3) void rnd_main(
    const float* __restrict__ obs, const uint16_t* __restrict__ Wall,
    const float* __restrict__ b1t, const float* __restrict__ b2t,
    const float* __restrict__ b1p, const float* __restrict__ b2p,
    const float* __restrict__ b3t, const float* __restrict__ b3p,
    float* __restrict__ rewards, float* __restrict__ sums) {
  __shared__ __align__(16) uint16_t Wbuf[128 * 136];  // 34 KB
  __shared__ float bs[4], bss[4];
  const int t    = threadIdx.x;
  const int lane = t & 63;
  const int wv   = t >> 6;
  const int n    = lane & 15;
  const int q    = lane >> 4;
  const int s0   = (blockIdx.x * 4 + wv) * 32;

  // ---- staging: plain padded copy (read formula == R1 global formula) ----
  auto stage64 = [&](const uint16_t* src) {   // 128x64, Kp=72
    #pragma unroll
    for (int i = 0; i < 4; ++i) {
      int g = i * 256 + t;                    // chunk 0..1023
      int d = g >> 3, c = g & 7;
      U8 u; u.i4 = *(const int4*)(src + g * 8);
      *(int4*)(Wbuf + d * 72 + c * 8) = u.i4;
    }
  };
  auto stage128 = [&](const uint16_t* src) {  // 128x128, Kp=136
    #pragma unroll
    for (int i = 0; i < 8; ++i) {
      int g = i * 256 + t;                    // chunk 0..2047
      int d = g >> 4, c = g & 15;
      U8 u; u.i4 = *(const int4*)(src + g * 8);
      *(int4*)(Wbuf + d * 136 + c * 8) = u.i4;
    }
  };
  // A-fragment from LDS: identical indexing to R1's afrag, base=Wbuf, stride=Kp
  auto afragL = [&](int Kp, int rt, int ks) -> v8s {
    U8 u; u.i4 = *(const int4*)(Wbuf + (rt * 16 + n) * Kp + ks * 32 + q * 8);
    return u.v;
  };

  auto obsfrag = [&](int ct, int ks) -> v8s {
    const float* p = obs + (size_t)(s0 + ct * 16 + n) * OBSD + ks * 32 + q * 8;
    float4 f0 = *(const float4*)p;
    float4 f1 = *(const float4*)(p + 4);
    U8 u;
    u.u[0] = pk2(f0.x, f0.y); u.u[1] = pk2(f0.z, f0.w);
    u.u[2] = pk2(f1.x, f1.y); u.u[3] = pk2(f1.z, f1.w);
    return u.v;
  };
  auto bias_init = [&](const float* b, v4f (&acc)[8][2]) {
    #pragma unroll
    for (int rt = 0; rt < 8; ++rt) {
      float4 bv = *(const float4*)(b + rt * 16 + q * 4);
      v4f c; c[0] = bv.x; c[1] = bv.y; c[2] = bv.z; c[3] = bv.w;
      acc[rt][0] = c; acc[rt][1] = c;
    }
  };
  auto pack_out = [&](v4f (&acc)[8][2], uint32_t (&P)[8][2][2]) {
    #pragma unroll
    for (int rt = 0; rt < 8; ++rt)
      #pragma unroll
      for (int ct = 0; ct < 2; ++ct) {
        v4f a = acc[rt][ct];
        a[0] = fmaxf(a[0], 0.f); a[1] = fmaxf(a[1], 0.f);
        a[2] = fmaxf(a[2], 0.f); a[3] = fmaxf(a[3], 0.f);
        P[rt][ct][0] = pk2(a[0], a[1]);
        P[rt][ct][1] = pk2(a[2], a[3]);
      }
  };
  // C-layout -> B-operand layout via cross-lane swaps (proven R1)
  auto bfrag_from = [&](uint32_t (&P)[8][2][2], int ks, int ct) -> v8s {
    uint32_t x0 = P[2 * ks][ct][0],     x1 = P[2 * ks][ct][1];
    uint32_t y0 = P[2 * ks + 1][ct][0], y1 = P[2 * ks + 1][ct][1];
    asm("v_permlane32_swap_b32 %0, %1" : "+v"(x0), "+v"(y0));
    asm("v_permlane16_swap_b32 %0, %1" : "+v"(x0), "+v"(y0));
    asm("v_permlane32_swap_b32 %0, %1" : "+v"(x1), "+v"(y1));
    asm("v_permlane16_swap_b32 %0, %1" : "+v"(x1), "+v"(y1));
    U8 u; u.u[0] = x0; u.u[1] = x1; u.u[2] = y0; u.u[3] = y1;
    return u.v;
  };
  auto layer1 = [&](const float* b, uint32_t (&P)[8][2][2]) {
    v4f acc[8][2];
    bias_init(b, acc);
    #pragma unroll
    for (int ks = 0; ks < 2; ++ks) {
      v8s bf0 = obsfrag(0, ks), bf1 = obsfrag(1, ks);
      #pragma unroll
      for (int rt = 0; rt < 8; ++rt) {
        v8s af = afragL(72, rt, ks);
        acc[rt][0] = __builtin_amdgcn_mfma_f32_16x16x32_bf16(af, bf0, acc[rt][0], 0, 0, 0);
        acc[rt][1] = __builtin_amdgcn_mfma_f32_16x16x32_bf16(af, bf1, acc[rt][1], 0, 0, 0);
      }
    }
    pack_out(acc, P);
  };
  auto layer2 = [&](const float* b, uint32_t (&Pin)[8][2][2], uint32_t (&Pout)[8][2][2]) {
    v4f acc[8][2];
    bias_init(b, acc);
    #pragma unroll
    for (int ks = 0; ks < 4; ++ks) {
      v8s bf0 = bfrag_from(Pin, ks, 0), bf1 = bfrag_from(Pin, ks, 1);
      #pragma unroll
      for (int rt = 0; rt < 8; ++rt) {
        v8s af = afragL(136, rt, ks);
        acc[rt][0] = __builtin_amdgcn_mfma_f32_16x16x32_bf16(af, bf0, acc[rt][0], 0, 0, 0);
        acc[rt][1] = __builtin_amdgcn_mfma_f32_16x16x32_bf16(af, bf1, acc[rt][1], 0, 0, 0);
      }
    }
    pack_out(acc, Pout);  // safe when Pout==Pin: all reads precede writes
  };

  uint32_t Pa[8][2][2];
  uint32_t Pt[8][2][2];

  // ---- target net ----
  stage64(Wall + 0);        __syncthreads();
  layer1(b1t, Pa);          __syncthreads();
  stage128(Wall + 8192);    __syncthreads();
  layer2(b2t, Pa, Pt);      __syncthreads();
  // ---- predictor net ----
  stage64(Wall + 40960);    __syncthreads();
  layer1(b1p, Pa);          __syncthreads();
  stage128(Wall + 49152);   __syncthreads();
  layer2(b2p, Pa, Pa);      __syncthreads();

  // ---- final layer: acc = (b3t-b3p) + W3t*H2t + (-W3p)*H2p == y_t - y_p ----
  v4f acc[8][2];
  #pragma unroll
  for (int rt = 0; rt < 8; ++rt) {
    float4 bt = *(const float4*)(b3t + rt * 16 + q * 4);
    float4 bp = *(const float4*)(b3p + rt * 16 + q * 4);
    v4f c; c[0] = bt.x - bp.x; c[1] = bt.y - bp.y; c[2] = bt.z - bp.z; c[3] = bt.w - bp.w;
    acc[rt][0] = c; acc[rt][1] = c;
  }
  stage128(Wall + 24576);   __syncthreads();
  // wait: barrier must precede reads; staging itself needs the previous
  // compute done reading Wbuf -> barrier BEFORE stage too (done above after l2p)
  #pragma unroll
  for (int ks = 0; ks < 4; ++ks) {
    v8s bf0 = bfrag_from(Pt, ks, 0), bf1 = bfrag_from(Pt, ks, 1);
    #pragma unroll
    for (int rt = 0; rt < 8; ++rt) {
      v8s af = afragL(136, rt, ks);
      acc[rt][0] = __builtin_amdgcn_mfma_f32_16x16x32_bf16(af, bf0, acc[rt][0], 0, 0, 0);
      acc[rt][1] = __builtin_amdgcn_mfma_f32_16x16x32_bf16(af, bf1, acc[rt][1], 0, 0, 0);
    }
  }
  __syncthreads();
  stage128(Wall + 65536);   __syncthreads();
  #pragma unroll
  for (int ks = 0; ks < 4; ++ks) {
    v8s bf0 = bfrag_from(Pa, ks, 0), bf1 = bfrag_from(Pa, ks, 1);
    #pragma unroll
    for (int rt = 0; rt < 8; ++rt) {
      v8s af = afragL(136, rt, ks);
      acc[rt][0] = __builtin_amdgcn_mfma_f32_16x16x32_bf16(af, bf0, acc[rt][0], 0, 0, 0);
      acc[rt][1] = __builtin_amdgcn_mfma_f32_16x16x32_bf16(af, bf1, acc[rt][1], 0, 0, 0);
    }
  }

  // ---- epilogue: reward = mean over 128 out-dims of diff^2 (verbatim R1) ----
  float p0 = 0.f, p1 = 0.f;
  #pragma unroll
  for (int rt = 0; rt < 8; ++rt) {
    v4f a0 = acc[rt][0], a1 = acc[rt][1];
    p0 += a0[0]*a0[0] + a0[1]*a0[1] + a0[2]*a0[2] + a0[3]*a0[3];
    p1 += a1[0]*a1[0] + a1[1]*a1[1] + a1[2]*a1[2] + a1[3]*a1[3];
  }
  p0 += __shfl_xor(p0, 32); p0 += __shfl_xor(p0, 16);
  p1 += __shfl_xor(p1, 32); p1 += __shfl_xor(p1, 16);
  float r0 = p0 * (1.0f / 128.0f), r1 = p1 * (1.0f / 128.0f);
  if (q == 0) {
    rewards[s0 + n]      = r0;
    rewards[s0 + 16 + n] = r1;
  }
  float s = r0 + r1, ss = r0 * r0 + r1 * r1;
  s  += __shfl_xor(s, 8);  s  += __shfl_xor(s, 4);  s  += __shfl_xor(s, 2);  s  += __shfl_xor(s, 1);
  ss += __shfl_xor(ss, 8); ss += __shfl_xor(ss, 4); ss += __shfl_xor(ss, 2); ss += __shfl_xor(ss, 1);
  if (lane == 0) { bs[wv] = s; bss[wv] = ss; }
  __syncthreads();
  if (t == 0) {
    atomicAdd(&sums[0], bs[0] + bs[1] + bs[2] + bs[3]);
    atomicAdd(&sums[1], bss[0] + bss[1] + bss[2] + bss[3]);
  }
}

// ---- normalize: Chan-merge with running stats ----
__global__ void rnd_norm(const float* __restrict__ rewards, const float* __restrict__ sums,
                         const float* __restrict__ rm, const float* __restrict__ rm2,
                         const float* __restrict__ rc, float* __restrict__ out) {
  float S = sums[0], SS = sums[1];
  float nb = (float)BATCH;
  float bm = S / nb;
  float bm2 = SS - nb * bm * bm;
  float cnt = rc[0];
  float newc = cnt + nb;
  float delta = bm - rm[0];
  float newmean = rm[0] + delta * nb / newc;
  float newm2 = rm2[0] + bm2 + delta * delta * cnt * nb / newc;
  float sd = (newc > 1.f) ? sqrtf(newm2 / (newc - 1.f)) : 1.f;
  float inv = 1.f / (sd + 1e-8f);
  int i = (blockIdx.x * 256 + threadIdx.x) * 4;
  float4 r = *(const float4*)(rewards + i);
  float4 o;
  o.x = (r.x - newmean) * inv; o.y = (r.y - newmean) * inv;
  o.z = (r.z - newmean) * inv; o.w = (r.w - newmean) * inv;
  *(float4*)(out + i) = o;
}

extern "C" void kernel_launch(void* const* d_in, const int* in_sizes, int n_in,
                              void* d_out, int out_size, void* d_ws, size_t ws_size,
                              hipStream_t stream) {
  const float* obs = (const float*)d_in[0];
  const float* rm  = (const float*)d_in[1];
  const float* rm2 = (const float*)d_in[2];
  const float* rc  = (const float*)d_in[3];
  const float* tW1 = (const float*)d_in[4];
  const float* tb1 = (const float*)d_in[5];
  const float* tW2 = (const float*)d_in[6];
  const float* tb2 = (const float*)d_in[7];
  const float* tW3 = (const float*)d_in[8];
  const float* tb3 = (const float*)d_in[9];
  const float* pW1 = (const float*)d_in[10];
  const float* pb1 = (const float*)d_in[11];
  const float* pW2 = (const float*)d_in[12];
  const float* pb2 = (const float*)d_in[13];
  const float* pW3 = (const float*)d_in[14];
  const float* pb3 = (const float*)d_in[15];

  float*    sums    = (float*)d_ws;
  float*    rewards = (float*)((char*)d_ws + 256);
  uint16_t* Wall    = (uint16_t*)((char*)d_ws + 256 + (size_t)BATCH * 4);

  rnd_prep<<<320, 256, 0, stream>>>(tW1, tW2, tW3, pW1, pW2, pW3, Wall, sums);
  rnd_main<<<BATCH / 128, 256, 0, stream>>>(obs, Wall, tb1, tb2, pb1, pb2, tb3, pb3,
                                            rewards, sums);
  rnd_norm<<<BATCH / 1024, 256, 0, stream>>>(rewards, sums, rm, rm2, rc, (float*)d_out);
}